// Round 3
// baseline (587.181 us; speedup 1.0000x reference)
//
#include <hip/hip_runtime.h>
#include <hip/hip_bf16.h>
#include <math.h>

typedef __bf16 bf16_t;
typedef bf16_t bf16x8 __attribute__((ext_vector_type(8)));
typedef float  f32x4  __attribute__((ext_vector_type(4)));

static constexpr int Bn = 16384;
static constexpr int Hn = 512;

__device__ __forceinline__ float sigm(float x) { return 1.0f / (1.0f + __expf(-x)); }

typedef __attribute__((address_space(3))) void lds_void;
typedef const __attribute__((address_space(1))) void gl_void;

__device__ __forceinline__ void glds16(const void* g, void* l) {
    __builtin_amdgcn_global_load_lds((gl_void*)g, (lds_void*)l, 16, 0, 0);
}

// comb[B][1024] bf16 = [input | hidden] converted
__global__ void convert_comb(const float* __restrict__ inp, const float* __restrict__ hid,
                             bf16_t* __restrict__ comb)
{
    size_t t = (size_t)blockIdx.x * blockDim.x + threadIdx.x;
    size_t r = t >> 7;
    int c8 = (int)(t & 127);
    const float* src = (c8 < 64) ? (inp + r * 512 + c8 * 8) : (hid + r * 512 + (c8 - 64) * 8);
    float4 a = ((const float4*)src)[0];
    float4 b = ((const float4*)src)[1];
    bf16x8 o;
    o[0] = (bf16_t)a.x; o[1] = (bf16_t)a.y; o[2] = (bf16_t)a.z; o[3] = (bf16_t)a.w;
    o[4] = (bf16_t)b.x; o[5] = (bf16_t)b.y; o[6] = (bf16_t)b.z; o[7] = (bf16_t)b.w;
    *(bf16x8*)(comb + t * 8) = o;
}

// dst[C][R] bf16 = transpose(src[R][C] fp32)
__global__ void transpose_bf16(const float* __restrict__ src, bf16_t* __restrict__ dst,
                               int R, int C)
{
    __shared__ float tile[32][33];
    const int x0 = blockIdx.x * 32, y0 = blockIdx.y * 32;
    const int tx = threadIdx.x & 31, ty = threadIdx.x >> 5;
#pragma unroll
    for (int i = 0; i < 32; i += 8)
        tile[ty + i][tx] = src[(size_t)(y0 + ty + i) * C + x0 + tx];
    __syncthreads();
#pragma unroll
    for (int i = 0; i < 32; i += 8)
        dst[(size_t)(x0 + ty + i) * R + y0 + tx] = (bf16_t)tile[tx][ty + i];
}

// C[M,N] = epi(A @ Bt^T + bias). Tile TM x 128, BK=64, 4 waves (2x2).
// LDS rows are 128B; swizzle: 16B slot ^= (row&7) [bf16] / ^= (row&7)<<1 [fp32].
// Linear glds dest + inverse-swizzled global source + swizzled ds_read (involution).
template<int EPI, int TM, bool AF32>
__global__ __launch_bounds__(256)
void gemm_k64(const void* __restrict__ Aptr, int lda,
              const bf16_t* __restrict__ Bt, int ldb,
              const float* __restrict__ bias, int K, int N,
              bf16_t* __restrict__ bout, float* __restrict__ fout,
              const bf16_t* __restrict__ gates, const float* __restrict__ cell)
{
    constexpr int MI = TM / 32;                 // frag rows per wave
    constexpr int ABYTES = TM * 64 * (AF32 ? 4 : 2);
    __shared__ __align__(16) char smem[ABYTES + 128 * 64 * 2];
    bf16_t* sB = (bf16_t*)(smem + ABYTES);

    const int tid = threadIdx.x, lane = tid & 63, wid = tid >> 6;
    const int wr = wid >> 1, wc = wid & 1;

    // bijective XCD swizzle (all grids are multiples of 8)
    const int nwg = gridDim.x;
    int bid = blockIdx.x;
    bid = (bid & 7) * (nwg >> 3) + (bid >> 3);
    const int gx = N >> 7;
    const int row0 = (bid / gx) * TM, col0 = (bid % gx) * 128;

    f32x4 acc[MI][4] = {};
    const int nk = K >> 6;

    const int l15 = lane & 15, kq = lane >> 4;

    for (int kt = 0; kt < nk; ++kt) {
        const int k0 = kt << 6;
        // ---- stage A (linear LDS dest, inverse-swizzled source)
        if constexpr (!AF32) {
            const bf16_t* Ab = (const bf16_t*)Aptr;
#pragma unroll
            for (int t = 0; t < TM / 32; ++t) {
                const int c8 = wid * (TM / 32) + t;      // 1KB chunk = 8 rows
                const int r = c8 * 8 + (lane >> 3);
                const int slot = (lane & 7) ^ (lane >> 3);   // ^ (r&7)
                glds16(Ab + (size_t)(row0 + r) * lda + k0 + slot * 8,
                       (bf16_t*)smem + c8 * 512);
            }
        } else {
            const float* Af = (const float*)Aptr;
#pragma unroll
            for (int t = 0; t < TM / 16; ++t) {
                const int c4 = wid * (TM / 16) + t;      // 1KB chunk = 4 rows
                const int r = c4 * 4 + (lane >> 4);
                const int slot = (lane & 15) ^ ((r & 7) << 1);
                glds16(Af + (size_t)(row0 + r) * lda + k0 + slot * 4,
                       (float*)smem + c4 * 256);
            }
        }
        // ---- stage B (128 x 64 bf16 = 16 chunks)
#pragma unroll
        for (int t = 0; t < 4; ++t) {
            const int c8 = wid * 4 + t;
            const int r = c8 * 8 + (lane >> 3);
            const int slot = (lane & 7) ^ (lane >> 3);
            glds16(Bt + (size_t)(col0 + r) * ldb + k0 + slot * 8, sB + c8 * 512);
        }
        __syncthreads();

        // ---- two K=32 sub-steps; load frags per step (caps VGPR)
#pragma unroll
        for (int ks = 0; ks < 2; ++ks) {
            bf16x8 bfr[4], af[MI];
#pragma unroll
            for (int j = 0; j < 4; ++j) {
                const int rb = wc * 64 + j * 16 + l15;
                const int slot = (ks * 4 + kq) ^ (l15 & 7);
                bfr[j] = *(const bf16x8*)&sB[rb * 64 + slot * 8];
            }
#pragma unroll
            for (int i = 0; i < MI; ++i) {
                const int ra = wr * (TM / 2) + i * 16 + l15;
                if constexpr (!AF32) {
                    const int slot = (ks * 4 + kq) ^ (l15 & 7);
                    af[i] = *(const bf16x8*)((bf16_t*)smem + ra * 64 + slot * 8);
                } else {
                    const int s0 = (ks * 8 + kq * 2) ^ ((l15 & 7) << 1);
                    const float* As = (const float*)smem + ra * 64;
                    float4 u = *(const float4*)(As + s0 * 4);
                    float4 v = *(const float4*)(As + s0 * 4 + 4);
                    af[i][0] = (bf16_t)u.x; af[i][1] = (bf16_t)u.y;
                    af[i][2] = (bf16_t)u.z; af[i][3] = (bf16_t)u.w;
                    af[i][4] = (bf16_t)v.x; af[i][5] = (bf16_t)v.y;
                    af[i][6] = (bf16_t)v.z; af[i][7] = (bf16_t)v.w;
                }
            }
#pragma unroll
            for (int i = 0; i < MI; ++i)
#pragma unroll
                for (int j = 0; j < 4; ++j)
                    acc[i][j] = __builtin_amdgcn_mfma_f32_16x16x32_bf16(af[i], bfr[j], acc[i][j], 0, 0, 0);
        }
        __syncthreads();
    }

    // ---- epilogue: C/D layout col = lane&15, row = 4*(lane>>4)+reg
    const int lr = (lane >> 4) * 4, lc = lane & 15;
#pragma unroll
    for (int i = 0; i < MI; ++i) {
#pragma unroll
        for (int j = 0; j < 4; ++j) {
#pragma unroll
            for (int r = 0; r < 4; ++r) {
                const int grow = row0 + wr * (TM / 2) + i * 16 + lr + r;
                const int gcol = col0 + wc * 64 + j * 16 + lc;
                float v = acc[i][j][r];
                if constexpr (EPI == 0) {
                    v += bias[gcol];
                    const float a = ((gcol >> 9) == 2) ? tanhf(v) : sigm(v);
                    bout[(size_t)grow * 2048 + gcol] = (bf16_t)a;
                } else if constexpr (EPI == 1) {
                    bout[(size_t)grow * 8192 + gcol] = (bf16_t)(v + bias[gcol]);
                } else {
                    const float ig = (float)gates[(size_t)grow * 2048 + gcol];
                    const float fg = (float)gates[(size_t)grow * 2048 + 512 + gcol];
                    const float cg = (float)gates[(size_t)grow * 2048 + 1024 + gcol];
                    const float og = (float)gates[(size_t)grow * 2048 + 1536 + gcol];
                    const float cv = cell[(size_t)grow * 512 + gcol];
                    const float ncv = fg * cv + ig * cg + 0.1f * v;
                    fout[(size_t)grow * 512 + gcol] = og * tanhf(ncv);
                    fout[(size_t)Bn * Hn + (size_t)grow * 512 + gcol] = ncv;
                }
            }
        }
    }
}

// Row softmax: reads bf16 logits packed in the row's first half, writes fp32 attn in place.
__global__ void softmax_mid(float* __restrict__ attn)
{
    const int row = blockIdx.x;
    float* rp = attn + (size_t)row * 4096;
    const bf16_t* lp = (const bf16_t*)rp;
    const int tid = threadIdx.x;

    float v[16];
    {
        bf16x8 h0 = ((const bf16x8*)lp)[tid];
        bf16x8 h1 = ((const bf16x8*)lp)[tid + 256];
#pragma unroll
        for (int k = 0; k < 8; ++k) { v[k] = (float)h0[k]; v[8 + k] = (float)h1[k]; }
    }
    float mx = v[0];
#pragma unroll
    for (int k = 1; k < 16; ++k) mx = fmaxf(mx, v[k]);
#pragma unroll
    for (int off = 32; off > 0; off >>= 1) mx = fmaxf(mx, __shfl_xor(mx, off));
    __shared__ float smx[4], ssm[4];
    if ((tid & 63) == 0) smx[tid >> 6] = mx;
    __syncthreads();
    mx = fmaxf(fmaxf(smx[0], smx[1]), fmaxf(smx[2], smx[3]));

    float sum = 0.0f;
#pragma unroll
    for (int k = 0; k < 16; ++k) { v[k] = __expf(v[k] - mx); sum += v[k]; }
#pragma unroll
    for (int off = 32; off > 0; off >>= 1) sum += __shfl_xor(sum, off);
    if ((tid & 63) == 0) ssm[tid >> 6] = sum;
    __syncthreads();
    sum = ssm[0] + ssm[1] + ssm[2] + ssm[3];

    const float inv = 1.0f / sum;
    float4 o0 = { v[0] * inv,  v[1] * inv,  v[2] * inv,  v[3] * inv };
    float4 o1 = { v[4] * inv,  v[5] * inv,  v[6] * inv,  v[7] * inv };
    float4 o2 = { v[8] * inv,  v[9] * inv,  v[10] * inv, v[11] * inv };
    float4 o3 = { v[12] * inv, v[13] * inv, v[14] * inv, v[15] * inv };
    ((float4*)rp)[tid * 2]             = o0;
    ((float4*)rp)[tid * 2 + 1]         = o1;
    ((float4*)rp)[(tid + 256) * 2]     = o2;
    ((float4*)rp)[(tid + 256) * 2 + 1] = o3;
}

extern "C" void kernel_launch(void* const* d_in, const int* in_sizes, int n_in,
                              void* d_out, int out_size, void* d_ws, size_t ws_size,
                              hipStream_t stream)
{
    const float* input  = (const float*)d_in[0];
    const float* hidden = (const float*)d_in[1];
    const float* cell   = (const float*)d_in[2];
    const float* Wg     = (const float*)d_in[3];
    const float* bg     = (const float*)d_in[4];
    const float* Wa     = (const float*)d_in[5];
    const float* ba     = (const float*)d_in[6];
    const float* Mem    = (const float*)d_in[7];

    float* out  = (float*)d_out;
    float* attn = out + 2ull * Bn * Hn;

    bf16_t* comb  = (bf16_t*)d_ws;                 // [B][1024]
    bf16_t* WgT   = comb + (size_t)Bn * 1024;      // [2048][1024]
    bf16_t* WaT   = WgT + (size_t)2048 * 1024;     // [4096][512]
    bf16_t* MemT  = WaT + (size_t)4096 * 512;      // [512][4096]
    bf16_t* gates = MemT + (size_t)512 * 4096;     // [B][2048]

    convert_comb<<<8192, 256, 0, stream>>>(input, hidden, comb);
    transpose_bf16<<<dim3(64, 32), 256, 0, stream>>>(Wg, WgT, 1024, 2048);
    transpose_bf16<<<dim3(128, 16), 256, 0, stream>>>(Wa, WaT, 512, 4096);
    transpose_bf16<<<dim3(16, 128), 256, 0, stream>>>(Mem, MemT, 4096, 512);

    // gates = act([x|h] @ Wg + bg)
    gemm_k64<0, 128, false><<<2048, 256, 0, stream>>>(comb, 1024, WgT, 1024, bg, 1024, 2048,
                                                      gates, nullptr, nullptr, nullptr);
    // bf16 logits -> d_out attn slots (packed)
    gemm_k64<1, 128, false><<<4096, 256, 0, stream>>>(comb + 512, 1024, WaT, 512, ba, 512, 4096,
                                                      (bf16_t*)attn, nullptr, nullptr, nullptr);
    // softmax in place (bf16 -> fp32)
    softmax_mid<<<Bn, 256, 0, stream>>>(attn);
    // mr = attn @ Mem fused with LSTM update (fp32 A, 64-row tiles for occupancy)
    gemm_k64<2, 64, true><<<1024, 256, 0, stream>>>(attn, 4096, MemT, 4096, nullptr, 4096, 512,
                                                    nullptr, out, gates, cell);
}

// Round 4
// 527.141 us; speedup vs baseline: 1.1139x; 1.1139x over previous
//
#include <hip/hip_runtime.h>
#include <hip/hip_bf16.h>
#include <math.h>

typedef __bf16 bf16_t;
typedef bf16_t bf16x8 __attribute__((ext_vector_type(8)));
typedef float  f32x4  __attribute__((ext_vector_type(4)));

static constexpr int Bn = 16384;
static constexpr int Hn = 512;

__device__ __forceinline__ float sigm(float x) { return 1.0f / (1.0f + __expf(-x)); }

typedef __attribute__((address_space(3))) void lds_void;
typedef const __attribute__((address_space(1))) void gl_void;

__device__ __forceinline__ void glds16(const void* g, void* l) {
    __builtin_amdgcn_global_load_lds((gl_void*)g, (lds_void*)l, 16, 0, 0);
}

// comb[B][1024] bf16 = [input | hidden] converted
__global__ void convert_comb(const float* __restrict__ inp, const float* __restrict__ hid,
                             bf16_t* __restrict__ comb)
{
    size_t t = (size_t)blockIdx.x * blockDim.x + threadIdx.x;
    size_t r = t >> 7;
    int c8 = (int)(t & 127);
    const float* src = (c8 < 64) ? (inp + r * 512 + c8 * 8) : (hid + r * 512 + (c8 - 64) * 8);
    float4 a = ((const float4*)src)[0];
    float4 b = ((const float4*)src)[1];
    bf16x8 o;
    o[0] = (bf16_t)a.x; o[1] = (bf16_t)a.y; o[2] = (bf16_t)a.z; o[3] = (bf16_t)a.w;
    o[4] = (bf16_t)b.x; o[5] = (bf16_t)b.y; o[6] = (bf16_t)b.z; o[7] = (bf16_t)b.w;
    *(bf16x8*)(comb + t * 8) = o;
}

// All three weight transposes in one launch: 3 x 2048 blocks of 32x32 tiles.
__global__ void transpose_all(const float* __restrict__ Wg, bf16_t* __restrict__ WgT,
                              const float* __restrict__ Wa, bf16_t* __restrict__ WaT,
                              const float* __restrict__ Mem, bf16_t* __restrict__ MemT)
{
    __shared__ float tile[32][33];
    int b = blockIdx.x;
    const float* src; bf16_t* dst; int R, C, gx;
    if (b < 2048)      { src = Wg;  dst = WgT;  R = 1024; C = 2048; gx = 64; }
    else if (b < 4096) { b -= 2048; src = Wa;  dst = WaT;  R = 512;  C = 4096; gx = 128; }
    else               { b -= 4096; src = Mem; dst = MemT; R = 4096; C = 512;  gx = 16; }
    const int x0 = (b % gx) * 32, y0 = (b / gx) * 32;
    const int tx = threadIdx.x & 31, ty = threadIdx.x >> 5;
#pragma unroll
    for (int i = 0; i < 32; i += 8)
        tile[ty + i][tx] = src[(size_t)(y0 + ty + i) * C + x0 + tx];
    __syncthreads();
#pragma unroll
    for (int i = 0; i < 32; i += 8)
        dst[(size_t)(x0 + ty + i) * R + y0 + tx] = (bf16_t)tile[tx][ty + i];
}

// C[M,N] = epi(A @ Bt^T + bias). A bf16 [M][lda], Bt bf16 [N][ldb] (K-major).
// 128x128 tile, BK=64, 4 waves 2x2. LDS rows 128B = 8 x 16B slots; swizzle slot ^= (row&7).
// Linear glds dest + inverse-swizzled global source + swizzled ds_read (involution).
// EPI 0: activated gates (stride 2048). EPI 1: bf16 logits packed (stride 8192).
// EPI 2: fused LSTM cell update -> fout.
template<int EPI>
__global__ __launch_bounds__(256)
void gemm_k64(const bf16_t* __restrict__ A, int lda,
              const bf16_t* __restrict__ Bt, int ldb,
              const float* __restrict__ bias, int K, int N,
              bf16_t* __restrict__ bout, float* __restrict__ fout,
              const bf16_t* __restrict__ gates, const float* __restrict__ cell)
{
    __shared__ __align__(16) bf16_t sA[128 * 64];
    __shared__ __align__(16) bf16_t sB[128 * 64];

    const int tid = threadIdx.x, lane = tid & 63, wid = tid >> 6;
    const int wr = wid >> 1, wc = wid & 1;

    // bijective XCD swizzle (all grids are multiples of 8)
    const int nwg = gridDim.x;
    int bid = blockIdx.x;
    bid = (bid & 7) * (nwg >> 3) + (bid >> 3);
    const int gx = N >> 7;
    const int row0 = (bid / gx) * 128, col0 = (bid % gx) * 128;

    f32x4 acc[4][4] = {};
    const int nk = K >> 6;
    const int l15 = lane & 15, kq = lane >> 4;

    for (int kt = 0; kt < nk; ++kt) {
        const int k0 = kt << 6;
        // ---- stage A+B: 16 chunks each, 1KB/chunk (8 rows), linear LDS dest
#pragma unroll
        for (int t = 0; t < 4; ++t) {
            const int c8 = wid * 4 + t;
            const int r = c8 * 8 + (lane >> 3);
            const int slot = (lane & 7) ^ (lane >> 3);     // inverse-swizzled source
            glds16(A + (size_t)(row0 + r) * lda + k0 + slot * 8, sA + c8 * 512);
            glds16(Bt + (size_t)(col0 + r) * ldb + k0 + slot * 8, sB + c8 * 512);
        }
        __syncthreads();

        // ---- two K=32 sub-steps; swizzled ds_read_b128 fragments
#pragma unroll
        for (int ks = 0; ks < 2; ++ks) {
            bf16x8 af[4], bfr[4];
#pragma unroll
            for (int j = 0; j < 4; ++j) {
                const int rb = wc * 64 + j * 16 + l15;
                const int slot = (ks * 4 + kq) ^ (l15 & 7);
                bfr[j] = *(const bf16x8*)&sB[rb * 64 + slot * 8];
                const int ra = wr * 64 + j * 16 + l15;
                af[j] = *(const bf16x8*)&sA[ra * 64 + slot * 8];
            }
#pragma unroll
            for (int i = 0; i < 4; ++i)
#pragma unroll
                for (int j = 0; j < 4; ++j)
                    acc[i][j] = __builtin_amdgcn_mfma_f32_16x16x32_bf16(af[i], bfr[j], acc[i][j], 0, 0, 0);
        }
        __syncthreads();
    }

    // ---- epilogue: C/D layout col = lane&15, row = 4*(lane>>4)+reg
    const int lr = (lane >> 4) * 4, lc = lane & 15;
#pragma unroll
    for (int i = 0; i < 4; ++i) {
#pragma unroll
        for (int j = 0; j < 4; ++j) {
#pragma unroll
            for (int r = 0; r < 4; ++r) {
                const int grow = row0 + wr * 64 + i * 16 + lr + r;
                const int gcol = col0 + wc * 64 + j * 16 + lc;
                float v = acc[i][j][r];
                if constexpr (EPI == 0) {
                    v += bias[gcol];
                    const float a = ((gcol >> 9) == 2) ? tanhf(v) : sigm(v);
                    bout[(size_t)grow * 2048 + gcol] = (bf16_t)a;
                } else if constexpr (EPI == 1) {
                    bout[(size_t)grow * 8192 + gcol] = (bf16_t)(v + bias[gcol]);
                } else {
                    const float ig = (float)gates[(size_t)grow * 2048 + gcol];
                    const float fg = (float)gates[(size_t)grow * 2048 + 512 + gcol];
                    const float cg = (float)gates[(size_t)grow * 2048 + 1024 + gcol];
                    const float og = (float)gates[(size_t)grow * 2048 + 1536 + gcol];
                    const float cv = cell[(size_t)grow * 512 + gcol];
                    const float ncv = fg * cv + ig * cg + 0.1f * v;
                    fout[(size_t)grow * 512 + gcol] = og * tanhf(ncv);
                    fout[(size_t)Bn * Hn + (size_t)grow * 512 + gcol] = ncv;
                }
            }
        }
    }
}

// Row softmax: packed bf16 logits in -> packed bf16 attn out (in place, same slots).
__global__ void softmax_mid(float* __restrict__ attn)
{
    const int row = blockIdx.x;
    float* rp = attn + (size_t)row * 4096;
    bf16_t* lp = (bf16_t*)rp;
    const int tid = threadIdx.x;

    float v[16];
    {
        bf16x8 h0 = ((const bf16x8*)lp)[tid];
        bf16x8 h1 = ((const bf16x8*)lp)[tid + 256];
#pragma unroll
        for (int k = 0; k < 8; ++k) { v[k] = (float)h0[k]; v[8 + k] = (float)h1[k]; }
    }
    float mx = v[0];
#pragma unroll
    for (int k = 1; k < 16; ++k) mx = fmaxf(mx, v[k]);
#pragma unroll
    for (int off = 32; off > 0; off >>= 1) mx = fmaxf(mx, __shfl_xor(mx, off));
    __shared__ float smx[4], ssm[4];
    if ((tid & 63) == 0) smx[tid >> 6] = mx;
    __syncthreads();
    mx = fmaxf(fmaxf(smx[0], smx[1]), fmaxf(smx[2], smx[3]));

    float sum = 0.0f;
#pragma unroll
    for (int k = 0; k < 16; ++k) { v[k] = __expf(v[k] - mx); sum += v[k]; }
#pragma unroll
    for (int off = 32; off > 0; off >>= 1) sum += __shfl_xor(sum, off);
    if ((tid & 63) == 0) ssm[tid >> 6] = sum;
    __syncthreads();
    sum = ssm[0] + ssm[1] + ssm[2] + ssm[3];

    const float inv = 1.0f / sum;
    bf16x8 o0, o1;
#pragma unroll
    for (int k = 0; k < 8; ++k) { o0[k] = (bf16_t)(v[k] * inv); o1[k] = (bf16_t)(v[8 + k] * inv); }
    ((bf16x8*)lp)[tid]       = o0;
    ((bf16x8*)lp)[tid + 256] = o1;
}

// Expand packed bf16 attn row (first half) -> full fp32 row, in place.
__global__ void expand_attn(float* __restrict__ attn)
{
    const int row = blockIdx.x;
    float* rp = attn + (size_t)row * 4096;
    const int t = threadIdx.x;
    bf16x8 h0 = ((const bf16x8*)rp)[2 * t];
    bf16x8 h1 = ((const bf16x8*)rp)[2 * t + 1];
    __syncthreads();                               // all reads before any write
    float4 o0 = { (float)h0[0], (float)h0[1], (float)h0[2], (float)h0[3] };
    float4 o1 = { (float)h0[4], (float)h0[5], (float)h0[6], (float)h0[7] };
    float4 o2 = { (float)h1[0], (float)h1[1], (float)h1[2], (float)h1[3] };
    float4 o3 = { (float)h1[4], (float)h1[5], (float)h1[6], (float)h1[7] };
    ((float4*)rp)[4 * t]     = o0;
    ((float4*)rp)[4 * t + 1] = o1;
    ((float4*)rp)[4 * t + 2] = o2;
    ((float4*)rp)[4 * t + 3] = o3;
}

extern "C" void kernel_launch(void* const* d_in, const int* in_sizes, int n_in,
                              void* d_out, int out_size, void* d_ws, size_t ws_size,
                              hipStream_t stream)
{
    const float* input  = (const float*)d_in[0];
    const float* hidden = (const float*)d_in[1];
    const float* cell   = (const float*)d_in[2];
    const float* Wg     = (const float*)d_in[3];
    const float* bg     = (const float*)d_in[4];
    const float* Wa     = (const float*)d_in[5];
    const float* ba     = (const float*)d_in[6];
    const float* Mem    = (const float*)d_in[7];

    float* out  = (float*)d_out;
    float* attn = out + 2ull * Bn * Hn;

    bf16_t* comb  = (bf16_t*)d_ws;                 // [B][1024]
    bf16_t* WgT   = comb + (size_t)Bn * 1024;      // [2048][1024]
    bf16_t* WaT   = WgT + (size_t)2048 * 1024;     // [4096][512]
    bf16_t* MemT  = WaT + (size_t)4096 * 512;      // [512][4096]
    bf16_t* gates = MemT + (size_t)512 * 4096;     // [B][2048]

    convert_comb<<<8192, 256, 0, stream>>>(input, hidden, comb);
    transpose_all<<<6144, 256, 0, stream>>>(Wg, WgT, Wa, WaT, Mem, MemT);

    // gates = act([x|h] @ Wg + bg)
    gemm_k64<0><<<2048, 256, 0, stream>>>(comb, 1024, WgT, 1024, bg, 1024, 2048,
                                          gates, nullptr, nullptr, nullptr);
    // bf16 logits packed into d_out attn rows
    gemm_k64<1><<<4096, 256, 0, stream>>>(comb + 512, 1024, WaT, 512, ba, 512, 4096,
                                          (bf16_t*)attn, nullptr, nullptr, nullptr);
    // softmax in place (packed bf16 -> packed bf16)
    softmax_mid<<<Bn, 256, 0, stream>>>(attn);
    // mr = attn @ Mem fused with LSTM update; A = packed bf16 attn, lda = 8192
    gemm_k64<2><<<512, 256, 0, stream>>>((const bf16_t*)attn, 8192, MemT, 4096, nullptr, 4096, 512,
                                         nullptr, out, gates, cell);
    // expand packed bf16 attn -> fp32 rows (final attn output)
    expand_attn<<<Bn, 256, 0, stream>>>(attn);
}